// Round 2
// baseline (360.184 us; speedup 1.0000x reference)
//
#include <hip/hip_runtime.h>
#include <stdint.h>

#define NCOMP 5
#define DM 1024
#define LN_EPS 1e-5f

typedef __attribute__((ext_vector_type(8))) __bf16 bf16x8;
typedef __attribute__((ext_vector_type(4))) float f32x4;

__device__ __forceinline__ unsigned short f2bf(float f) {
    unsigned u = __builtin_bit_cast(unsigned, f);
    u += 0x7fffu + ((u >> 16) & 1u);   // round-to-nearest-even
    return (unsigned short)(u >> 16);
}
__device__ __forceinline__ float bf2f(unsigned short h) {
    return __builtin_bit_cast(float, ((unsigned)h) << 16);
}

// -------- kernel 1: fused compartment LayerNorm, fp32 -> bf16 --------
// block = 128 threads (2 waves), one token per block, 8 elems/thread
__global__ __launch_bounds__(128) void ln_kernel(
    const float* __restrict__ x, const int* __restrict__ cid,
    const float* __restrict__ gamma, const float* __restrict__ beta,
    const float* __restrict__ scale, unsigned short* __restrict__ y)
{
    const int t = blockIdx.x;
    const int tid = threadIdx.x;
    const float* xp = x + (size_t)t * DM + tid * 8;
    const float4 a = *(const float4*)xp;
    const float4 b = *(const float4*)(xp + 4);
    float s  = a.x + a.y + a.z + a.w + b.x + b.y + b.z + b.w;
    float ss = a.x*a.x + a.y*a.y + a.z*a.z + a.w*a.w
             + b.x*b.x + b.y*b.y + b.z*b.z + b.w*b.w;
#pragma unroll
    for (int off = 32; off > 0; off >>= 1) {
        s  += __shfl_down(s, off);
        ss += __shfl_down(ss, off);
    }
    __shared__ float red[4];
    if ((tid & 63) == 0) { red[tid >> 6] = s; red[2 + (tid >> 6)] = ss; }
    __syncthreads();
    const float sum = red[0] + red[1];
    const float sqs = red[2] + red[3];
    const float mu  = sum * (1.0f / DM);
    const float var = sqs * (1.0f / DM) - mu * mu;
    const float rs  = rsqrtf(var + LN_EPS);
    const int craw  = cid[t];
    const bool valid = craw < NCOMP;           // reference: valid = id < NC
    const int c = min(max(craw, 0), NCOMP - 1);
    const float sc = scale[c];
    const float* gp = gamma + c * DM + tid * 8;
    const float* bp = beta  + c * DM + tid * 8;
    const float4 g0 = *(const float4*)gp;
    const float4 g1 = *(const float4*)(gp + 4);
    const float4 b0 = *(const float4*)bp;
    const float4 b1 = *(const float4*)(bp + 4);
    float o[8];
    o[0] = valid ? ((a.x - mu) * rs * g0.x + b0.x) * sc : a.x;
    o[1] = valid ? ((a.y - mu) * rs * g0.y + b0.y) * sc : a.y;
    o[2] = valid ? ((a.z - mu) * rs * g0.z + b0.z) * sc : a.z;
    o[3] = valid ? ((a.w - mu) * rs * g0.w + b0.w) * sc : a.w;
    o[4] = valid ? ((b.x - mu) * rs * g1.x + b1.x) * sc : b.x;
    o[5] = valid ? ((b.y - mu) * rs * g1.y + b1.y) * sc : b.y;
    o[6] = valid ? ((b.z - mu) * rs * g1.z + b1.z) * sc : b.z;
    o[7] = valid ? ((b.w - mu) * rs * g1.w + b1.w) * sc : b.w;
    uint4 p;
    p.x = (unsigned)f2bf(o[0]) | ((unsigned)f2bf(o[1]) << 16);
    p.y = (unsigned)f2bf(o[2]) | ((unsigned)f2bf(o[3]) << 16);
    p.z = (unsigned)f2bf(o[4]) | ((unsigned)f2bf(o[5]) << 16);
    p.w = (unsigned)f2bf(o[6]) | ((unsigned)f2bf(o[7]) << 16);
    *(uint4*)(y + (size_t)t * DM + tid * 8) = p;
}

// -------- kernel 2: W fp32 -> bf16 --------
__global__ __launch_bounds__(256) void cvt_kernel(
    const float* __restrict__ W, unsigned short* __restrict__ Wb)
{
    const int i = (blockIdx.x * 256 + threadIdx.x) * 4;
    const float4 v = *(const float4*)(W + i);
    uint2 p;
    p.x = (unsigned)f2bf(v.x) | ((unsigned)f2bf(v.y) << 16);
    p.y = (unsigned)f2bf(v.z) | ((unsigned)f2bf(v.w) << 16);
    *(uint2*)(Wb + i) = p;
}

// -------- kernel 3: C = A * Bt^T + A + bias --------
// A = y bf16 [M,1024] row-major; Bt = W bf16 [1024(N rows),1024(K)] row-major
__device__ __forceinline__ void gld_lds16(const unsigned short* g, unsigned short* l) {
    __builtin_amdgcn_global_load_lds(
        (const __attribute__((address_space(1))) unsigned int*)(uintptr_t)g,
        (__attribute__((address_space(3))) unsigned int*)(uintptr_t)l,
        16, 0, 0);
}

__global__ __launch_bounds__(256) void gemm_kernel(
    const unsigned short* __restrict__ A,
    const unsigned short* __restrict__ Bt,
    const float* __restrict__ bias,
    float* __restrict__ C, int M)
{
    constexpr int K = 1024, N = 1024, BK = 32, TM = 128, TN = 128;
    // 16 KB: K-loop uses it as As(8K)+Bs(8K); epilogue reuses it as 4x4KB
    // per-wave f32 transpose slices.
    __shared__ __align__(16) unsigned short smem[TM * BK + TN * BK];
    unsigned short* As = smem;
    unsigned short* Bs = smem + TM * BK;

    const int tid  = threadIdx.x;
    const int bm   = blockIdx.x * TM;
    const int bn   = blockIdx.y * TN;
    const int lane = tid & 63;
    const int wave = tid >> 6;
    const int wm   = (wave >> 1) * 64;   // wave m-offset in tile
    const int wn   = (wave & 1) * 64;    // wave n-offset in tile

    // staging: chunk c = tid (issue 0) and tid+256 (issue 1); chunk -> row c/4, col (c%4)*8
    const int r0 = tid >> 2;
    const int c0 = (tid & 3) * 8;
    const unsigned short* Ag  = A  + (size_t)(bm + r0) * K + c0;
    const unsigned short* Ag2 = A  + (size_t)(bm + 64 + r0) * K + c0;
    const unsigned short* Bg  = Bt + (size_t)(bn + r0) * K + c0;
    const unsigned short* Bg2 = Bt + (size_t)(bn + 64 + r0) * K + c0;
    unsigned short* Asl  = &As[(size_t)tid * 8];
    unsigned short* Asl2 = &As[(size_t)(tid + 256) * 8];
    unsigned short* Bsl  = &Bs[(size_t)tid * 8];
    unsigned short* Bsl2 = &Bs[(size_t)(tid + 256) * 8];

    f32x4 acc[4][4] = {};

    const int quad = lane >> 4;        // 0..3
    const int qk = quad * 8;           // k-offset of this lane's fragment
    const int fr = lane & 15;          // m (A) / n (B) index within 16-tile

    for (int k0 = 0; k0 < K; k0 += BK) {
        __syncthreads();               // prev iter's LDS reads done
        gld_lds16(Ag  + k0, Asl);
        gld_lds16(Ag2 + k0, Asl2);
        gld_lds16(Bg  + k0, Bsl);
        gld_lds16(Bg2 + k0, Bsl2);
        __syncthreads();               // staging complete

        bf16x8 af[4], bfr[4];
#pragma unroll
        for (int i = 0; i < 4; i++)
            af[i] = *(const bf16x8*)&As[(wm + i * 16 + fr) * BK + qk];
#pragma unroll
        for (int i = 0; i < 4; i++)
            bfr[i] = *(const bf16x8*)&Bs[(wn + i * 16 + fr) * BK + qk];
#pragma unroll
        for (int mi = 0; mi < 4; mi++)
#pragma unroll
            for (int ni = 0; ni < 4; ni++)
                acc[mi][ni] = __builtin_amdgcn_mfma_f32_16x16x32_bf16(
                    af[mi], bfr[ni], acc[mi][ni], 0, 0, 0);
    }

    // ---- epilogue: out = acc + y + bias, coalesced via LDS transpose ----
    // C/D layout: col = lane&15 (fr), row = quad*4 + reg
    __syncthreads();                       // all waves done reading As/Bs
    float* tb = (float*)smem + wave * 1024;   // 4 KB per-wave slice (16 rows x 64 cols)
    const int erow = lane >> 3;            // 0..7
    const int ecol = (lane & 7) * 4;       // 0,4,...,28
#pragma unroll
    for (int mi = 0; mi < 4; mi++) {
#pragma unroll
        for (int ni = 0; ni < 4; ni++)
#pragma unroll
            for (int r = 0; r < 4; r++)
                tb[(quad * 4 + r) * 64 + ni * 16 + fr] = acc[mi][ni][r];
        __syncthreads();                   // slice visible (uniform control flow)
#pragma unroll
        for (int j = 0; j < 4; j++) {
            const int row = (j >> 1) * 8 + erow;     // 0..15
            const int col = (j & 1) * 32 + ecol;     // 0..60
            const int gr = bm + wm + mi * 16 + row;
            const int gc = bn + wn + col;
            const float4 v = *(const float4*)&tb[row * 64 + col];
            const ushort4 yv = *(const ushort4*)(A + (size_t)gr * K + gc); // K==N
            const float4 bv = *(const float4*)&bias[gc];
            float4 o;
            o.x = v.x + bf2f(yv.x) + bv.x;
            o.y = v.y + bf2f(yv.y) + bv.y;
            o.z = v.z + bf2f(yv.z) + bv.z;
            o.w = v.w + bf2f(yv.w) + bv.w;
            *(float4*)&C[(size_t)gr * N + gc] = o;   // 8 rows x 128B full lines per inst
        }
        __syncthreads();                   // before next mi overwrites slice
    }
}

extern "C" void kernel_launch(void* const* d_in, const int* in_sizes, int n_in,
                              void* d_out, int out_size, void* d_ws, size_t ws_size,
                              hipStream_t stream)
{
    const float* x     = (const float*)d_in[0];
    const int*   cid   = (const int*)d_in[1];
    const float* gamma = (const float*)d_in[2];
    const float* beta  = (const float*)d_in[3];
    const float* scale = (const float*)d_in[4];
    const float* W     = (const float*)d_in[5];
    const float* bias  = (const float*)d_in[6];
    float* out = (float*)d_out;

    const int M = in_sizes[0] / DM;           // 32768 tokens
    unsigned short* yb = (unsigned short*)d_ws;            // M*1024 bf16 = 64 MB
    unsigned short* Wb = yb + (size_t)M * DM;              // 1024*1024 bf16 = 2 MB

    ln_kernel<<<M, 128, 0, stream>>>(x, cid, gamma, beta, scale, yb);
    cvt_kernel<<<(DM * DM) / 1024, 256, 0, stream>>>(W, Wb);
    dim3 grid(M / 128, DM / 128);
    gemm_kernel<<<grid, 256, 0, stream>>>(yb, Wb, bias, out, M);
}

// Round 3
// 344.757 us; speedup vs baseline: 1.0447x; 1.0447x over previous
//
#include <hip/hip_runtime.h>
#include <stdint.h>

#define NCOMP 5
#define DM 1024
#define LN_EPS 1e-5f

typedef __attribute__((ext_vector_type(8))) __bf16 bf16x8;
typedef __attribute__((ext_vector_type(4))) float f32x4;

__device__ __forceinline__ unsigned short f2bf(float f) {
    unsigned u = __builtin_bit_cast(unsigned, f);
    u += 0x7fffu + ((u >> 16) & 1u);   // round-to-nearest-even
    return (unsigned short)(u >> 16);
}

// -------- kernel 1: fused compartment LayerNorm + (W+I)->bf16 --------
// block = 128 threads, 4 units per block. unit < M: token LN; else: W row.
__global__ __launch_bounds__(128) void ln_w_kernel(
    const float* __restrict__ x, const int* __restrict__ cid,
    const float* __restrict__ gamma, const float* __restrict__ beta,
    const float* __restrict__ scale, const float* __restrict__ W,
    unsigned short* __restrict__ y, unsigned short* __restrict__ Wb, int M)
{
    const int tid = threadIdx.x;
    __shared__ float red[8];
    const int base = blockIdx.x * 4;
#pragma unroll
    for (int u = 0; u < 4; u++) {
        const int t = base + u;                 // block-uniform
        if (t < M) {
            const float* xp = x + (size_t)t * DM + tid * 8;
            const float4 a = *(const float4*)xp;
            const float4 b = *(const float4*)(xp + 4);
            float s  = a.x + a.y + a.z + a.w + b.x + b.y + b.z + b.w;
            float ss = a.x*a.x + a.y*a.y + a.z*a.z + a.w*a.w
                     + b.x*b.x + b.y*b.y + b.z*b.z + b.w*b.w;
#pragma unroll
            for (int off = 32; off > 0; off >>= 1) {
                s  += __shfl_down(s, off);
                ss += __shfl_down(ss, off);
            }
            float* rr = red + (u & 1) * 4;      // parity slot: no WAR hazard
            if ((tid & 63) == 0) { rr[tid >> 6] = s; rr[2 + (tid >> 6)] = ss; }
            __syncthreads();
            const float mu  = (rr[0] + rr[1]) * (1.0f / DM);
            const float var = (rr[2] + rr[3]) * (1.0f / DM) - mu * mu;
            const float rs  = rsqrtf(var + LN_EPS);
            const int craw  = cid[t];
            const bool valid = craw < NCOMP;    // reference guard
            const int c = min(max(craw, 0), NCOMP - 1);
            const float sc = scale[c];
            const float* gp = gamma + c * DM + tid * 8;
            const float* bp = beta  + c * DM + tid * 8;
            const float4 g0 = *(const float4*)gp;
            const float4 g1 = *(const float4*)(gp + 4);
            const float4 b0 = *(const float4*)bp;
            const float4 b1 = *(const float4*)(bp + 4);
            float o[8];
            o[0] = valid ? ((a.x - mu) * rs * g0.x + b0.x) * sc : a.x;
            o[1] = valid ? ((a.y - mu) * rs * g0.y + b0.y) * sc : a.y;
            o[2] = valid ? ((a.z - mu) * rs * g0.z + b0.z) * sc : a.z;
            o[3] = valid ? ((a.w - mu) * rs * g0.w + b0.w) * sc : a.w;
            o[4] = valid ? ((b.x - mu) * rs * g1.x + b1.x) * sc : b.x;
            o[5] = valid ? ((b.y - mu) * rs * g1.y + b1.y) * sc : b.y;
            o[6] = valid ? ((b.z - mu) * rs * g1.z + b1.z) * sc : b.z;
            o[7] = valid ? ((b.w - mu) * rs * g1.w + b1.w) * sc : b.w;
            uint4 p;
            p.x = (unsigned)f2bf(o[0]) | ((unsigned)f2bf(o[1]) << 16);
            p.y = (unsigned)f2bf(o[2]) | ((unsigned)f2bf(o[3]) << 16);
            p.z = (unsigned)f2bf(o[4]) | ((unsigned)f2bf(o[5]) << 16);
            p.w = (unsigned)f2bf(o[6]) | ((unsigned)f2bf(o[7]) << 16);
            *(uint4*)(y + (size_t)t * DM + tid * 8) = p;
        } else {
            const int row = t - M;              // 0..DM-1
            const float* wp = W + (size_t)row * DM + tid * 8;
            const float4 a = *(const float4*)wp;
            const float4 b = *(const float4*)(wp + 4);
            float o[8] = {a.x, a.y, a.z, a.w, b.x, b.y, b.z, b.w};
            const int d = row - tid * 8;        // fold identity: out = y*(W+I)^T + b
            if (d >= 0 && d < 8) o[d] += 1.0f;
            uint4 p;
            p.x = (unsigned)f2bf(o[0]) | ((unsigned)f2bf(o[1]) << 16);
            p.y = (unsigned)f2bf(o[2]) | ((unsigned)f2bf(o[3]) << 16);
            p.z = (unsigned)f2bf(o[4]) | ((unsigned)f2bf(o[5]) << 16);
            p.w = (unsigned)f2bf(o[6]) | ((unsigned)f2bf(o[7]) << 16);
            *(uint4*)(Wb + (size_t)row * DM + tid * 8) = p;
        }
    }
}

// -------- kernel 2: C = A * Bp^T + bias (Bp = W + I, bf16) --------
// A bf16 [M,1024] row-major; Bp bf16 [1024(N),1024(K)] row-major
__device__ __forceinline__ void gld_lds16(const unsigned short* g, unsigned short* l) {
    __builtin_amdgcn_global_load_lds(
        (const __attribute__((address_space(1))) unsigned int*)(uintptr_t)g,
        (__attribute__((address_space(3))) unsigned int*)(uintptr_t)l,
        16, 0, 0);
}

__global__ __launch_bounds__(256) void gemm_kernel(
    const unsigned short* __restrict__ A,
    const unsigned short* __restrict__ Bp,
    const float* __restrict__ bias,
    float* __restrict__ C, int M)
{
    constexpr int K = 1024, N = 1024, BK = 32, TM = 128, NIT = K / BK;
    // double buffer: buf b at smem + b*8192 shorts (As 4096 + Bs 4096) = 32 KB
    __shared__ __align__(16) unsigned short smem[16384];

    const int tid  = threadIdx.x;
    const int bm   = blockIdx.x * TM;
    const int bn   = blockIdx.y * TM;
    const int lane = tid & 63;
    const int wave = tid >> 6;
    const int wm   = (wave >> 1) * 64;
    const int wn   = (wave & 1) * 64;

    const int r0 = tid >> 2;
    const int c0 = (tid & 3) * 8;
    const unsigned short* Ag  = A  + (size_t)(bm + r0) * K + c0;
    const unsigned short* Ag2 = A  + (size_t)(bm + 64 + r0) * K + c0;
    const unsigned short* Bg  = Bp + (size_t)(bn + r0) * K + c0;
    const unsigned short* Bg2 = Bp + (size_t)(bn + 64 + r0) * K + c0;

    f32x4 acc[4][4] = {};
    const int quad = lane >> 4;
    const int qk = quad * 8;
    const int fr = lane & 15;

    // prologue: stage tile 0 into buf 0
    {
        unsigned short* s = smem;
        gld_lds16(Ag, s + (size_t)tid * 8);
        gld_lds16(Ag2, s + (size_t)(tid + 256) * 8);
        gld_lds16(Bg, s + 4096 + (size_t)tid * 8);
        gld_lds16(Bg2, s + 4096 + (size_t)(tid + 256) * 8);
    }
    __syncthreads();   // drains vmcnt(0): buf0 valid

#pragma unroll 2
    for (int i = 0; i < NIT; i++) {
        // prefetch tile i+1 into the other buffer BEFORE computing tile i
        if (i + 1 < NIT) {
            const int kn = (i + 1) * BK;
            unsigned short* s = smem + ((i + 1) & 1) * 8192;
            gld_lds16(Ag  + kn, s + (size_t)tid * 8);
            gld_lds16(Ag2 + kn, s + (size_t)(tid + 256) * 8);
            gld_lds16(Bg  + kn, s + 4096 + (size_t)tid * 8);
            gld_lds16(Bg2 + kn, s + 4096 + (size_t)(tid + 256) * 8);
        }
        const unsigned short* As = smem + (i & 1) * 8192;
        const unsigned short* Bs = As + 4096;
        bf16x8 af[4], bfr[4];
#pragma unroll
        for (int j = 0; j < 4; j++)
            af[j] = *(const bf16x8*)&As[(wm + j * 16 + fr) * BK + qk];
#pragma unroll
        for (int j = 0; j < 4; j++)
            bfr[j] = *(const bf16x8*)&Bs[(wn + j * 16 + fr) * BK + qk];
#pragma unroll
        for (int mi = 0; mi < 4; mi++)
#pragma unroll
            for (int ni = 0; ni < 4; ni++)
                acc[mi][ni] = __builtin_amdgcn_mfma_f32_16x16x32_bf16(
                    af[mi], bfr[ni], acc[mi][ni], 0, 0, 0);
        // single barrier: prefetch drain overlapped by the MFMA block above;
        // also protects buf(i&1) from being overwritten next iteration
        __syncthreads();
    }

    // ---- epilogue: out = acc + bias, per-wave LDS transpose (no barriers) ----
    // C/D layout: col = fr, row = quad*4 + reg. Padded stride 68 breaks conflicts.
    float* tb = (float*)smem + wave * 1088;   // 16 rows x 68 floats, per-wave private
    const int erow = lane >> 3;               // 0..7
    const int ecol = (lane & 7) * 4;          // 0..28
    float4 bv0 = *(const float4*)&bias[bn + wn + ecol];
    float4 bv1 = *(const float4*)&bias[bn + wn + 32 + ecol];
#pragma unroll
    for (int mi = 0; mi < 4; mi++) {
#pragma unroll
        for (int ni = 0; ni < 4; ni++)
#pragma unroll
            for (int r = 0; r < 4; r++)
                tb[(quad * 4 + r) * 68 + ni * 16 + fr] = acc[mi][ni][r];
        // same-wave LDS: in-order pipe + compiler lgkmcnt waits; no barrier
#pragma unroll
        for (int j = 0; j < 4; j++) {
            const int row  = (j >> 1) * 8 + erow;        // 0..15
            const int colg = (j & 1) * 32 + ecol;        // 0..60
            const int gr = bm + wm + mi * 16 + row;
            const float4 v = *(const float4*)&tb[row * 68 + colg];
            const float4 bv = (j & 1) ? bv1 : bv0;
            float4 o;
            o.x = v.x + bv.x; o.y = v.y + bv.y;
            o.z = v.z + bv.z; o.w = v.w + bv.w;
            *(float4*)&C[(size_t)gr * N + bn + wn + colg] = o;  // full 128B lines
        }
    }
}

extern "C" void kernel_launch(void* const* d_in, const int* in_sizes, int n_in,
                              void* d_out, int out_size, void* d_ws, size_t ws_size,
                              hipStream_t stream)
{
    const float* x     = (const float*)d_in[0];
    const int*   cid   = (const int*)d_in[1];
    const float* gamma = (const float*)d_in[2];
    const float* beta  = (const float*)d_in[3];
    const float* scale = (const float*)d_in[4];
    const float* W     = (const float*)d_in[5];
    const float* bias  = (const float*)d_in[6];
    float* out = (float*)d_out;

    const int M = in_sizes[0] / DM;                        // 32768 tokens
    unsigned short* yb = (unsigned short*)d_ws;            // M*1024 bf16 = 64 MB
    unsigned short* Wb = yb + (size_t)M * DM;              // 1024*1024 bf16 = 2 MB

    ln_w_kernel<<<(M + DM) / 4, 128, 0, stream>>>(x, cid, gamma, beta, scale, W, yb, Wb, M);
    dim3 grid(M / 128, DM / 128);
    gemm_kernel<<<grid, 256, 0, stream>>>(yb, Wb, bias, out, M);
}